// Round 15
// baseline (1574.830 us; speedup 1.0000x reference)
//
#include <hip/hip_runtime.h>
#include <stdint.h>

typedef __attribute__((ext_vector_type(8))) short short8;
typedef __attribute__((ext_vector_type(4))) float f32x4;
typedef __attribute__((ext_vector_type(4))) int i32x4;

#define DMODEL 768
#define HID    2048
#define MROWS  4096   // 2*2048 tokens

// B-spline constants: h = (4-(-4))/(16-3) = 8/13
#define KINVH  (13.0f/8.0f)
#define KNOT0  (-4.0f - 3.0f*(8.0f/13.0f))

// Relaxed barrier: LDS-ordering only (lgkmcnt), NO vmcnt drain — in-flight
// global loads span the barrier; their consumers get the compiler's automatic
// vmcnt wait. Validated r13/r14 (absmax clean). sched_barrier per rule #18.
#define BAR_LDS() do { asm volatile("s_waitcnt lgkmcnt(0)" ::: "memory"); \
                       __builtin_amdgcn_s_barrier(); \
                       __builtin_amdgcn_sched_barrier(0); } while (0)

__device__ __forceinline__ unsigned short f2bf(float f) {
  unsigned int u = __float_as_uint(f);
  unsigned int r = (u + 0x7FFFu + ((u >> 16) & 1u)) >> 16;
  return (unsigned short)r;
}

// ---- weight f32 -> bf16, packed in MFMA-fragment order ----
// dst 16B-unit layout: [cb=col/16][kt2=k/32][q=l>>4][c16=l&15]; a B-fragment
// load (fixed cb,kt2) is lane-linear: addr = base + lane*16B.
template<int DIN>
__global__ void __launch_bounds__(256) conv_pack(const float* __restrict__ src,
                                                 unsigned short* __restrict__ dst,
                                                 int total_waves) {
  constexpr int NK2 = DIN / 2;               // number of 32-wide k halves
  int gw = blockIdx.x * 4 + (threadIdx.x >> 6);
  if (gw >= total_waves) return;
  int l   = threadIdx.x & 63;
  int cb  = gw / NK2;
  int kt2 = gw % NK2;
  int c16 = l & 15, q = l >> 4;
  int col = cb * 16 + c16;
  const float* s = src + ((size_t)col * DIN + kt2 * 2 + (q >> 1)) * 16 + (q & 1) * 8;
  float4 v0 = *(const float4*)s;
  float4 v1 = *(const float4*)(s + 4);
  short8 o;
  o[0] = (short)f2bf(v0.x); o[1] = (short)f2bf(v0.y);
  o[2] = (short)f2bf(v0.z); o[3] = (short)f2bf(v0.w);
  o[4] = (short)f2bf(v1.x); o[5] = (short)f2bf(v1.y);
  o[6] = (short)f2bf(v1.z); o[7] = (short)f2bf(v1.w);
  unsigned short* d = dst + (((size_t)cb * NK2 + kt2) * 64 + q * 16 + c16) * 8;
  *(short8*)d = o;
}

// ---- split-K=2 reduce, in place: p[i] = p[i] + p[i+n4] ----
__global__ void __launch_bounds__(256) reduce2(float4* __restrict__ p, int n4) {
  int i = blockIdx.x * 256 + threadIdx.x;
  if (i >= n4) return;
  float4 a = p[i], b = p[i + n4];
  float4 r;
  r.x = a.x + b.x; r.y = a.y + b.y; r.z = a.z + b.z; r.w = a.w + b.w;
  p[i] = r;
}

// ---- split-K=4 reduce: out[i] = sum over 4 planes ----
__global__ void __launch_bounds__(256) reduce4(const float4* __restrict__ p,
                                               float4* __restrict__ out, int n4) {
  int i = blockIdx.x * 256 + threadIdx.x;
  if (i >= n4) return;
  float4 a = p[i], b = p[i + n4], c = p[i + 2 * n4], d = p[i + 3 * n4];
  float4 r;
  r.x = a.x + b.x + c.x + d.x;
  r.y = a.y + b.y + c.y + d.y;
  r.z = a.z + b.z + c.z + d.z;
  r.w = a.w + b.w + c.w + d.w;
  out[i] = r;
}

// ---- fused basis + GEMM: A double-buffered in LDS, ONE barrier per K-step ----
// C[n,o] = sum_{d,k} basis(X[n,d])_k * Wb'[o,k]
// Tile: BM=64 x BN=256, BK=64. 4 waves in 1x4; wave tile 64x64 (FM=FN=4).
// Step kt: ds_read A(kt) from smA[kt&1]; basis(kt+1) -> smA[(kt+1)&1]
// (write target last read in step kt-1; read source written in step kt-1 —
// both guarded by the single end-of-step lgkmcnt(0)+s_barrier). Basis VALU
// now sits between the A ds_reads and the MFMAs with no dependence -> the
// scheduler interleaves VALU and MFMA issue (separate pipes), and barrier
// count halves. B stays direct global->register (packed Wb'), loaded after
// the MFMAs, latency spanning the barrier into the next step.
template<int DIN, int DOUT, int SPLITK>
__global__ void __launch_bounds__(256, 4)
kan_gemm(const float* __restrict__ X, const unsigned short* __restrict__ Wb,
         float* __restrict__ Out) {
  constexpr int BM  = 64;
  constexpr int BN  = 256;
  constexpr int NK  = (DIN * 16) / 64;
  constexpr int NK2 = DIN / 2;
  constexpr int NKS = NK / SPLITK;
  static_assert(NKS % 2 == 0, "K-step count must be even for buffer parity");
  constexpr int GX  = MROWS / BM;          // 64
  constexpr int GY  = DOUT / BN;
  constexpr int CPX = (GX * GY) / 8;       // blocks per XCD (nwg%8==0, bijective)
  __shared__ __align__(16) char smA[2 * BM * 128];   // 2 x 8KB swizzled basis tiles

  const int tid  = threadIdx.x;
  const int lane = tid & 63;
  const int wid  = tid >> 6;

  // XCD-chunked remap
  const int d    = blockIdx.x + blockIdx.y * GX;
  const int lf   = (d & 7) * CPX + (d >> 3);
  const int brow = (lf % GX) * BM;
  const int bcol = (lf / GX) * BN;
  const int kt0  = blockIdx.z * NKS;
  const int kt1  = kt0 + NKS;

  f32x4 acc[4][4];
#pragma unroll
  for (int m = 0; m < 4; ++m)
#pragma unroll
    for (int n = 0; n < 4; ++n) acc[m][n] = (f32x4){0.f, 0.f, 0.f, 0.f};

  // A-fragment LDS addressing (constant per lane; buffer offset folds into
  // the ds-instruction immediate — swizzle bits (<128) disjoint from 8192)
  int a_base[4], a_sw[4];
#pragma unroll
  for (int m = 0; m < 4; ++m) {
    int row   = m * 16 + (lane & 15);
    a_base[m] = row * 128 + ((lane >> 4) * 16);
    a_sw[m]   = (row & 7) << 4;
  }

  // B-fragment pointers: frag n, lane-linear in packed layout
  const unsigned short* bp[4];
#pragma unroll
  for (int n = 0; n < 4; ++n)
    bp[n] = Wb + ((size_t)(bcol / 16 + wid * 4 + n) * NK2 + (size_t)kt0 * 2) * 512
               + lane * 8;

  const int br_ = tid >> 2;        // basis row
  const int bd_ = tid & 3;         // basis d-col within the 4-col step
  const float* xrow = X + (size_t)(brow + br_) * DIN + bd_;

  // basis for one (row, d-col) -> swizzled scatter into buffer WB (literal)
  auto BASIS = [&](float xv, int WB) {
    char* smp = smA + WB * (BM * 128);
    float u  = (xv - KNOT0) * KINVH;
    float uf = floorf(u);
    int   jj = (int)uf;
    float t  = u - uf;
    float t2 = t * t, t3 = t2 * t;
    float p0 = (1.0f / 6.0f) * (1.0f - 3.0f * t + 3.0f * t2 - t3);
    float p1 = (1.0f / 6.0f) * (4.0f - 6.0f * t2 + 3.0f * t3);
    float p2 = (1.0f / 6.0f) * (1.0f + 3.0f * t + 3.0f * t2 - 3.0f * t3);
    float p3 = (1.0f / 6.0f) * t3;

    int base = br_ * 128 + bd_ * 32;
    int sw   = (br_ & 7) << 4;
    *(i32x4*)(smp + (base ^ sw))        = (i32x4){0, 0, 0, 0};
    *(i32x4*)(smp + ((base + 16) ^ sw)) = (i32x4){0, 0, 0, 0};
    unsigned short q0 = f2bf(p0), q1 = f2bf(p1), q2 = f2bf(p2), q3 = f2bf(p3);
    int k0 = jj - 3;
    if ((unsigned)(k0 + 0) < 16u) *(unsigned short*)(smp + ((base + (k0 + 0) * 2) ^ sw)) = q0;
    if ((unsigned)(k0 + 1) < 16u) *(unsigned short*)(smp + ((base + (k0 + 1) * 2) ^ sw)) = q1;
    if ((unsigned)(k0 + 2) < 16u) *(unsigned short*)(smp + ((base + (k0 + 2) * 2) ^ sw)) = q2;
    if ((unsigned)(k0 + 3) < 16u) *(unsigned short*)(smp + ((base + (k0 + 3) * 2) ^ sw)) = q3;
  };

  // ---- prologue: B(kt0) in flight; basis(kt0) -> buf 0; xv = X(kt0+1)
  short8 bv[2][4];
#pragma unroll
  for (int n = 0; n < 4; ++n) {
    bv[0][n] = *(const short8*)(bp[n]);
    bv[1][n] = *(const short8*)(bp[n] + 512);
    bp[n] += 1024;
  }
  BASIS(xrow[(size_t)kt0 * 4], 0);
  float xv = xrow[(size_t)(kt0 + 1) * 4];
  BAR_LDS();

  // one K-step: read A from buf RB, write basis(kt+1) to buf WB
  auto STEP = [&](int kt, int RB, int WB) {
    const bool more = (kt + 1 < kt1);
    const char* smR = smA + RB * (BM * 128);

    // A fragments kk=0 (4 ds_read_b128; latency hides under basis VALU)
    short8 a0[4];
#pragma unroll
    for (int m = 0; m < 4; ++m)
      a0[m] = *(const short8*)(smR + (a_base[m] ^ a_sw[m]));

    // basis(kt+1) into the other buffer — independent of this step's MFMAs,
    // so VALU/MFMA co-issue; plus next-X prefetch
    if (more) {
      BASIS(xv, WB);
      int ktn = (kt + 2 < kt1) ? kt + 2 : kt1 - 1;
      xv = xrow[(size_t)ktn * 4];
    }

    // MFMA kk=0
#pragma unroll
    for (int m = 0; m < 4; ++m)
#pragma unroll
      for (int n = 0; n < 4; ++n)
        acc[m][n] = __builtin_amdgcn_mfma_f32_16x16x32_bf16(a0[m], bv[0][n], acc[m][n], 0, 0, 0);

    // A fragments kk=1 + MFMA
    short8 a1[4];
#pragma unroll
    for (int m = 0; m < 4; ++m)
      a1[m] = *(const short8*)(smR + ((a_base[m] + 64) ^ a_sw[m]));
#pragma unroll
    for (int m = 0; m < 4; ++m)
#pragma unroll
      for (int n = 0; n < 4; ++n)
        acc[m][n] = __builtin_amdgcn_mfma_f32_16x16x32_bf16(a1[m], bv[1][n], acc[m][n], 0, 0, 0);

    // issue B(kt+1) (WAR-safe after MFMA issue; latency spans the barrier)
    if (more) {
#pragma unroll
      for (int n = 0; n < 4; ++n) {
        bv[0][n] = *(const short8*)(bp[n]);
        bv[1][n] = *(const short8*)(bp[n] + 512);
        bp[n] += 1024;
      }
    }

    // single barrier: flush basis writes; license next step's buffer swap
    BAR_LDS();
  };

  for (int kt = kt0; kt < kt1; kt += 2) {
    STEP(kt,     0, 1);
    STEP(kt + 1, 1, 0);
  }

  // ---- epilogue: C/D layout col=lane&15, row=(lane>>4)*4+q
  float* outp = Out + (size_t)blockIdx.z * MROWS * DOUT;
#pragma unroll
  for (int m = 0; m < 4; ++m)
#pragma unroll
    for (int n = 0; n < 4; ++n)
#pragma unroll
      for (int q = 0; q < 4; ++q) {
        int grow = brow + m * 16 + (lane >> 4) * 4 + q;
        int gcol = bcol + wid * 64 + n * 16 + (lane & 15);
        outp[(size_t)grow * DOUT + gcol] = acc[m][n][q];
      }
}

extern "C" void kernel_launch(void* const* d_in, const int* in_sizes, int n_in,
                              void* d_out, int out_size, void* d_ws, size_t ws_size,
                              hipStream_t stream) {
  const float* x  = (const float*)d_in[0];   // (2,2048,768) f32 -> (4096,768)
  const float* w1 = (const float*)d_in[1];   // (2048,768,16) f32
  const float* w2 = (const float*)d_in[2];   // (768,2048,16) f32
  float* out = (float*)d_out;                // (4096,768) f32

  // ws timeline (128 MiB):
  //   [0, 48M)   : w1b' (phase 1), then w2b' (phase 2, after GEMM1)
  //   [48M, 80M) : GEMM1 partial plane 0 -> becomes h (f32) after reduce2
  //   [80M, 112M): GEMM1 partial plane 1 (dead after reduce2)
  //   [80M, 128M): GEMM2 partial planes 0..3 (overwrites dead plane 1)
  char* ws = (char*)d_ws;
  unsigned short* wgb   = (unsigned short*)ws;                  // 50,331,648 B
  float*          part1 = (float*)(ws + 50331648);              // 2 x 33,554,432 B
  float*          hbf   = part1;                                // alias: plane 0
  float*          part2 = (float*)(ws + 83886080);              // 4 x 12,582,912 B (end = 128MiB)

  // phase 1: layer 1
  {
    const int waves = (HID / 16) * (DMODEL / 2);   // 128 * 384 = 49152
    conv_pack<DMODEL><<<waves / 4, 256, 0, stream>>>(w1, wgb, waves);
  }
  kan_gemm<DMODEL, HID, 2>
      <<<dim3(MROWS / 64, HID / 256, 2), 256, 0, stream>>>(x, wgb, part1);
  const int hn4 = (MROWS * HID) / 4;         // 2,097,152
  reduce2<<<hn4 / 256, 256, 0, stream>>>((float4*)part1, hn4);   // h = plane0

  // phase 2: layer 2 (pack w2 now that w1b' is dead)
  {
    const int waves = (DMODEL / 16) * (HID / 2);   // 48 * 1024 = 49152
    conv_pack<HID><<<waves / 4, 256, 0, stream>>>(w2, wgb, waves);
  }
  kan_gemm<HID, DMODEL, 4>
      <<<dim3(MROWS / 64, DMODEL / 256, 4), 256, 0, stream>>>(hbf, wgb, part2);
  const int rn4 = (MROWS * DMODEL) / 4;      // 786,432
  reduce4<<<rn4 / 256, 256, 0, stream>>>((const float4*)part2, (float4*)out, rn4);
}

// Round 16
// 1517.392 us; speedup vs baseline: 1.0379x; 1.0379x over previous
//
#include <hip/hip_runtime.h>
#include <stdint.h>

typedef __attribute__((ext_vector_type(8))) short short8;
typedef __attribute__((ext_vector_type(4))) float f32x4;
typedef __attribute__((ext_vector_type(4))) int i32x4;

#define DMODEL 768
#define HID    2048
#define MROWS  4096   // 2*2048 tokens

// B-spline constants: h = (4-(-4))/(16-3) = 8/13
#define KINVH  (13.0f/8.0f)
#define KNOT0  (-4.0f - 3.0f*(8.0f/13.0f))

__device__ __forceinline__ unsigned short f2bf(float f) {
  unsigned int u = __float_as_uint(f);
  unsigned int r = (u + 0x7FFFu + ((u >> 16) & 1u)) >> 16;
  return (unsigned short)r;
}

// ---- weight f32 -> bf16, packed in MFMA-fragment order ----
// dst 16B-unit layout: [cb=col/16][kt2=k/32][q=l>>4][c16=l&15]; a B-fragment
// load (fixed cb,kt2) is lane-linear: addr = base + lane*16B.
template<int DIN>
__global__ void __launch_bounds__(256) conv_pack(const float* __restrict__ src,
                                                 unsigned short* __restrict__ dst,
                                                 int total_waves) {
  constexpr int NK2 = DIN / 2;               // number of 32-wide k halves
  int gw = blockIdx.x * 4 + (threadIdx.x >> 6);
  if (gw >= total_waves) return;
  int l   = threadIdx.x & 63;
  int cb  = gw / NK2;
  int kt2 = gw % NK2;
  int c16 = l & 15, q = l >> 4;
  int col = cb * 16 + c16;
  const float* s = src + ((size_t)col * DIN + kt2 * 2 + (q >> 1)) * 16 + (q & 1) * 8;
  float4 v0 = *(const float4*)s;
  float4 v1 = *(const float4*)(s + 4);
  short8 o;
  o[0] = (short)f2bf(v0.x); o[1] = (short)f2bf(v0.y);
  o[2] = (short)f2bf(v0.z); o[3] = (short)f2bf(v0.w);
  o[4] = (short)f2bf(v1.x); o[5] = (short)f2bf(v1.y);
  o[6] = (short)f2bf(v1.z); o[7] = (short)f2bf(v1.w);
  unsigned short* d = dst + (((size_t)cb * NK2 + kt2) * 64 + q * 16 + c16) * 8;
  *(short8*)d = o;
}

// ---- split-K=2 reduce, in place: p[i] = p[i] + p[i+n4] ----
__global__ void __launch_bounds__(256) reduce2(float4* __restrict__ p, int n4) {
  int i = blockIdx.x * 256 + threadIdx.x;
  if (i >= n4) return;
  float4 a = p[i], b = p[i + n4];
  float4 r;
  r.x = a.x + b.x; r.y = a.y + b.y; r.z = a.z + b.z; r.w = a.w + b.w;
  p[i] = r;
}

// ---- split-K=4 reduce: out[i] = sum over 4 planes ----
__global__ void __launch_bounds__(256) reduce4(const float4* __restrict__ p,
                                               float4* __restrict__ out, int n4) {
  int i = blockIdx.x * 256 + threadIdx.x;
  if (i >= n4) return;
  float4 a = p[i], b = p[i + n4], c = p[i + 2 * n4], d = p[i + 3 * n4];
  float4 r;
  r.x = a.x + b.x + c.x + d.x;
  r.y = a.y + b.y + c.y + d.y;
  r.z = a.z + b.z + c.z + d.z;
  r.w = a.w + b.w + c.w + d.w;
  out[i] = r;
}

// ---- fused basis + GEMM: A double-buffered in LDS, ONE barrier per K-step ----
// C[n,o] = sum_{d,k} basis(X[n,d])_k * Wb'[o,k]
// Tile: BM=64 x BN=256, BK=64. 4 waves in 1x4; wave tile 64x64 (FM=FN=4).
// Step kt order (r15 spill fixed — BASIS FIRST so its temps die before a[]):
//   BASIS(kt+1) -> smA[WB]; X-prefetch; a=read smA[RB] kk0; MFMA kk0;
//   a=read kk1 (same regs); MFMA kk1; B(kt+1)->bv; __syncthreads.
// Single barrier licenses both hazards: WB was read in step kt-1, RB was
// written in step kt-1. Non-acc live set matches r13 (fits 64 VGPR + 64 AGPR
// = 128 total -> 4 waves/SIMD). Barrier count halves vs r13 (192 -> 96).
template<int DIN, int DOUT, int SPLITK>
__global__ void __launch_bounds__(256, 4)
kan_gemm(const float* __restrict__ X, const unsigned short* __restrict__ Wb,
         float* __restrict__ Out) {
  constexpr int BM  = 64;
  constexpr int BN  = 256;
  constexpr int NK  = (DIN * 16) / 64;
  constexpr int NK2 = DIN / 2;
  constexpr int NKS = NK / SPLITK;
  static_assert(NKS % 2 == 0, "even K-steps for buffer parity");
  constexpr int GX  = MROWS / BM;          // 64
  constexpr int GY  = DOUT / BN;
  constexpr int CPX = (GX * GY) / 8;       // blocks per XCD (nwg%8==0, bijective)
  __shared__ __align__(16) char smA[2][BM * 128];   // 2 x 8KB swizzled basis tiles

  const int tid  = threadIdx.x;
  const int lane = tid & 63;
  const int wid  = tid >> 6;

  // XCD-chunked remap
  const int d    = blockIdx.x + blockIdx.y * GX;
  const int lf   = (d & 7) * CPX + (d >> 3);
  const int brow = (lf % GX) * BM;
  const int bcol = (lf / GX) * BN;
  const int kt0  = blockIdx.z * NKS;
  const int kt1  = kt0 + NKS;

  f32x4 acc[4][4];
#pragma unroll
  for (int m = 0; m < 4; ++m)
#pragma unroll
    for (int n = 0; n < 4; ++n) acc[m][n] = (f32x4){0.f, 0.f, 0.f, 0.f};

  // A-fragment LDS addressing (constant per lane)
  int a_base[4], a_sw[4];
#pragma unroll
  for (int m = 0; m < 4; ++m) {
    int row   = m * 16 + (lane & 15);
    a_base[m] = row * 128 + ((lane >> 4) * 16);
    a_sw[m]   = (row & 7) << 4;
  }

  // B-fragment pointers: frag n, lane-linear in packed layout
  const unsigned short* bp[4];
#pragma unroll
  for (int n = 0; n < 4; ++n)
    bp[n] = Wb + ((size_t)(bcol / 16 + wid * 4 + n) * NK2 + (size_t)kt0 * 2) * 512
               + lane * 8;

  const int br_ = tid >> 2;        // basis row
  const int bd_ = tid & 3;         // basis d-col within the 4-col step
  const float* xrow = X + (size_t)(brow + br_) * DIN + bd_;

  // basis scatter into buffer (buf index is a literal at every call site)
  auto BASIS = [&](float xv, char* smp) {
    float u  = (xv - KNOT0) * KINVH;
    float uf = floorf(u);
    int   jj = (int)uf;
    float t  = u - uf;
    float t2 = t * t, t3 = t2 * t;
    float p0 = (1.0f / 6.0f) * (1.0f - 3.0f * t + 3.0f * t2 - t3);
    float p1 = (1.0f / 6.0f) * (4.0f - 6.0f * t2 + 3.0f * t3);
    float p2 = (1.0f / 6.0f) * (1.0f + 3.0f * t + 3.0f * t2 - 3.0f * t3);
    float p3 = (1.0f / 6.0f) * t3;

    int base = br_ * 128 + bd_ * 32;
    int sw   = (br_ & 7) << 4;
    *(i32x4*)(smp + (base ^ sw))        = (i32x4){0, 0, 0, 0};
    *(i32x4*)(smp + ((base + 16) ^ sw)) = (i32x4){0, 0, 0, 0};
    unsigned short q0 = f2bf(p0), q1 = f2bf(p1), q2 = f2bf(p2), q3 = f2bf(p3);
    int k0 = jj - 3;
    if ((unsigned)(k0 + 0) < 16u) *(unsigned short*)(smp + ((base + (k0 + 0) * 2) ^ sw)) = q0;
    if ((unsigned)(k0 + 1) < 16u) *(unsigned short*)(smp + ((base + (k0 + 1) * 2) ^ sw)) = q1;
    if ((unsigned)(k0 + 2) < 16u) *(unsigned short*)(smp + ((base + (k0 + 2) * 2) ^ sw)) = q2;
    if ((unsigned)(k0 + 3) < 16u) *(unsigned short*)(smp + ((base + (k0 + 3) * 2) ^ sw)) = q3;
  };

  // ---- prologue: B(kt0) in flight; basis(kt0) -> buf 0; xv = X(kt0+1)
  short8 bv[2][4];
#pragma unroll
  for (int n = 0; n < 4; ++n) {
    bv[0][n] = *(const short8*)(bp[n]);
    bv[1][n] = *(const short8*)(bp[n] + 512);
    bp[n] += 1024;
  }
  BASIS(xrow[(size_t)kt0 * 4], &smA[0][0]);
  float xv = xrow[(size_t)(kt0 + 1) * 4];
  __syncthreads();

  // one K-step: BASIS(kt+1)->WB first (temps die early), then read RB + MFMA
  auto STEP = [&](int kt, char* smR, char* smW) {
    const bool more = (kt + 1 < kt1);

    if (more) {
      BASIS(xv, smW);
      int ktn = (kt + 2 < kt1) ? kt + 2 : kt1 - 1;
      xv = xrow[(size_t)ktn * 4];
    }

    // kk=0: read + MFMA (a[] reused for kk=1 — r13 register shape)
    short8 a[4];
#pragma unroll
    for (int m = 0; m < 4; ++m)
      a[m] = *(const short8*)(smR + (a_base[m] ^ a_sw[m]));
#pragma unroll
    for (int m = 0; m < 4; ++m)
#pragma unroll
      for (int n = 0; n < 4; ++n)
        acc[m][n] = __builtin_amdgcn_mfma_f32_16x16x32_bf16(a[m], bv[0][n], acc[m][n], 0, 0, 0);

    // kk=1
#pragma unroll
    for (int m = 0; m < 4; ++m)
      a[m] = *(const short8*)(smR + ((a_base[m] + 64) ^ a_sw[m]));
#pragma unroll
    for (int m = 0; m < 4; ++m)
#pragma unroll
      for (int n = 0; n < 4; ++n)
        acc[m][n] = __builtin_amdgcn_mfma_f32_16x16x32_bf16(a[m], bv[1][n], acc[m][n], 0, 0, 0);

    // issue B(kt+1) (WAR-safe after MFMA issue)
    if (more) {
#pragma unroll
      for (int n = 0; n < 4; ++n) {
        bv[0][n] = *(const short8*)(bp[n]);
        bv[1][n] = *(const short8*)(bp[n] + 512);
        bp[n] += 1024;
      }
    }

    __syncthreads();   // single barrier: WB visible, RB reads done
  };

  for (int kt = kt0; kt < kt1; kt += 2) {
    STEP(kt,     &smA[0][0], &smA[1][0]);
    STEP(kt + 1, &smA[1][0], &smA[0][0]);
  }

  // ---- epilogue: C/D layout col=lane&15, row=(lane>>4)*4+q
  float* outp = Out + (size_t)blockIdx.z * MROWS * DOUT;
#pragma unroll
  for (int m = 0; m < 4; ++m)
#pragma unroll
    for (int n = 0; n < 4; ++n)
#pragma unroll
      for (int q = 0; q < 4; ++q) {
        int grow = brow + m * 16 + (lane >> 4) * 4 + q;
        int gcol = bcol + wid * 64 + n * 16 + (lane & 15);
        outp[(size_t)grow * DOUT + gcol] = acc[m][n][q];
      }
}

extern "C" void kernel_launch(void* const* d_in, const int* in_sizes, int n_in,
                              void* d_out, int out_size, void* d_ws, size_t ws_size,
                              hipStream_t stream) {
  const float* x  = (const float*)d_in[0];   // (2,2048,768) f32 -> (4096,768)
  const float* w1 = (const float*)d_in[1];   // (2048,768,16) f32
  const float* w2 = (const float*)d_in[2];   // (768,2048,16) f32
  float* out = (float*)d_out;                // (4096,768) f32

  // ws timeline (128 MiB):
  //   [0, 48M)   : w1b' (phase 1), then w2b' (phase 2, after GEMM1)
  //   [48M, 80M) : GEMM1 partial plane 0 -> becomes h (f32) after reduce2
  //   [80M, 112M): GEMM1 partial plane 1 (dead after reduce2)
  //   [80M, 128M): GEMM2 partial planes 0..3 (overwrites dead plane 1)
  char* ws = (char*)d_ws;
  unsigned short* wgb   = (unsigned short*)ws;                  // 50,331,648 B
  float*          part1 = (float*)(ws + 50331648);              // 2 x 33,554,432 B
  float*          hbf   = part1;                                // alias: plane 0
  float*          part2 = (float*)(ws + 83886080);              // 4 x 12,582,912 B (end = 128MiB)

  // phase 1: layer 1
  {
    const int waves = (HID / 16) * (DMODEL / 2);   // 128 * 384 = 49152
    conv_pack<DMODEL><<<waves / 4, 256, 0, stream>>>(w1, wgb, waves);
  }
  kan_gemm<DMODEL, HID, 2>
      <<<dim3(MROWS / 64, HID / 256, 2), 256, 0, stream>>>(x, wgb, part1);
  const int hn4 = (MROWS * HID) / 4;         // 2,097,152
  reduce2<<<hn4 / 256, 256, 0, stream>>>((float4*)part1, hn4);   // h = plane0

  // phase 2: layer 2 (pack w2 now that w1b' is dead)
  {
    const int waves = (DMODEL / 16) * (HID / 2);   // 48 * 1024 = 49152
    conv_pack<HID><<<waves / 4, 256, 0, stream>>>(w2, wgb, waves);
  }
  kan_gemm<HID, DMODEL, 4>
      <<<dim3(MROWS / 64, DMODEL / 256, 4), 256, 0, stream>>>(hbf, wgb, part2);
  const int rn4 = (MROWS * DMODEL) / 4;      // 786,432
  reduce4<<<rn4 / 256, 256, 0, stream>>>((const float4*)part2, (float4*)out, rn4);
}

// Round 17
// 496.380 us; speedup vs baseline: 3.1726x; 3.0569x over previous
//
#include <hip/hip_runtime.h>
#include <hip/hip_bf16.h>
#include <stdint.h>

typedef __attribute__((ext_vector_type(8))) short short8;
typedef __attribute__((ext_vector_type(16))) float f32x16;
typedef __attribute__((ext_vector_type(4))) float f32x4;
typedef __attribute__((ext_vector_type(4))) int i32x4;

#define DMODEL 768
#define HID    2048
#define MROWS  4096   // 2*2048 tokens

// B-spline constants: h = (4-(-4))/(16-3) = 8/13
#define KINVH  (13.0f/8.0f)
#define KNOT0  (-4.0f - 3.0f*(8.0f/13.0f))

__device__ __forceinline__ unsigned short f2bf(float f) {
  __hip_bfloat16 h = __float2bfloat16(f);   // single v_cvt on gfx950 (RNE)
  return *reinterpret_cast<unsigned short*>(&h);
}

// ---- weight f32 -> bf16, packed in 32x32x16-MFMA fragment order ----
// One wave per (cb32 = col/32, kg = k/16). Lane l holds col = cb32*32+(l&31),
// k = kg*16 + (l>>5)*8 .. +8  (8 bf16 = 16B). dst unit (cb32,kg) is 1KB,
// lane-linear: dst + ((cb32*KDIM16 + kg)*64 + l)*8 shorts. A B-fragment load
// for (cb32, kg) is then one coalesced wave load: base + lane*16B.
template<int DIN>
__global__ void __launch_bounds__(256) conv_pack32(const float* __restrict__ src,
                                                   unsigned short* __restrict__ dst,
                                                   int total_waves) {
  constexpr int KD16 = DIN;                  // number of 16-wide k slices
  int gw = blockIdx.x * 4 + (threadIdx.x >> 6);
  if (gw >= total_waves) return;
  int l    = threadIdx.x & 63;
  int cb32 = gw / KD16;
  int kg   = gw % KD16;
  int col  = cb32 * 32 + (l & 31);
  int k    = kg * 16 + (l >> 5) * 8;
  const float* s = src + (size_t)col * (DIN * 16) + k;
  float4 v0 = *(const float4*)s;
  float4 v1 = *(const float4*)(s + 4);
  short8 o;
  o[0] = (short)f2bf(v0.x); o[1] = (short)f2bf(v0.y);
  o[2] = (short)f2bf(v0.z); o[3] = (short)f2bf(v0.w);
  o[4] = (short)f2bf(v1.x); o[5] = (short)f2bf(v1.y);
  o[6] = (short)f2bf(v1.z); o[7] = (short)f2bf(v1.w);
  unsigned short* d = dst + (((size_t)cb32 * KD16 + kg) * 64 + l) * 8;
  *(short8*)d = o;
}

// ---- split-K=2 reduce, in place: p[i] = p[i] + p[i+n4] ----
__global__ void __launch_bounds__(256) reduce2(float4* __restrict__ p, int n4) {
  int i = blockIdx.x * 256 + threadIdx.x;
  if (i >= n4) return;
  float4 a = p[i], b = p[i + n4];
  float4 r;
  r.x = a.x + b.x; r.y = a.y + b.y; r.z = a.z + b.z; r.w = a.w + b.w;
  p[i] = r;
}

// ---- split-K=4 reduce: out[i] = sum over 4 planes ----
__global__ void __launch_bounds__(256) reduce4(const float4* __restrict__ p,
                                               float4* __restrict__ out, int n4) {
  int i = blockIdx.x * 256 + threadIdx.x;
  if (i >= n4) return;
  float4 a = p[i], b = p[i + n4], c = p[i + 2 * n4], d = p[i + 3 * n4];
  float4 r;
  r.x = a.x + b.x + c.x + d.x;
  r.y = a.y + b.y + c.y + d.y;
  r.z = a.z + b.z + c.z + d.z;
  r.w = a.w + b.w + c.w + d.w;
  out[i] = r;
}

// ---- fused basis + GEMM: r13 two-barrier skeleton, 32x32x16 MFMA ----
// C[n,o] = sum_{d,k} basis(X[n,d])_k * Wb'[o,k]
// Tile: BM=64 x BN=256, BK=64. 4 waves in 1x4; wave tile 64x64:
// FM=FN=2 frags of 32, 4 k-slices of 16 -> 16 MFMA/wave-step (vs 32 with
// 16x16x32) — attacks the measured issue-slot bound (~372 slots vs 312-cyc
// step budget). A from LDS (8KB, swizzled; 4-way conflict on 32-row frags,
// LDS pipe has headroom); B direct global->register from 32-col packed Wb'.
// Basis slimmed: p2(t)=p1(1-t) symmetry + Horner + HW bf16 cvt.
template<int DIN, int DOUT, int SPLITK>
__global__ void __launch_bounds__(256, 4)
kan_gemm(const float* __restrict__ X, const unsigned short* __restrict__ Wb,
         float* __restrict__ Out) {
  constexpr int BM  = 64;
  constexpr int BN  = 256;
  constexpr int NK  = (DIN * 16) / 64;     // K-steps of 64
  constexpr int NKS = NK / SPLITK;
  constexpr int KD16 = DIN;                // 16-wide k slices total
  constexpr int GX  = MROWS / BM;          // 64
  constexpr int GY  = DOUT / BN;
  constexpr int CPX = (GX * GY) / 8;       // blocks per XCD (nwg%8==0, bijective)
  __shared__ __align__(16) char smA[BM * 128];   // 64 rows x 64 bf16 (swizzled) = 8KB

  const int tid  = threadIdx.x;
  const int lane = tid & 63;
  const int wid  = tid >> 6;

  // XCD-chunked remap
  const int d    = blockIdx.x + blockIdx.y * GX;
  const int lf   = (d & 7) * CPX + (d >> 3);
  const int brow = (lf % GX) * BM;
  const int bcol = (lf / GX) * BN;
  const int kt0  = blockIdx.z * NKS;
  const int kt1  = kt0 + NKS;

  f32x16 acc[2][2];
#pragma unroll
  for (int m = 0; m < 2; ++m)
#pragma unroll
    for (int n = 0; n < 2; ++n)
#pragma unroll
      for (int q = 0; q < 16; ++q) acc[m][n][q] = 0.f;

  // A-fragment LDS addressing: row = m*32 + (lane&31), 16B at (lane>>5)*16;
  // per k-slice add ks*32 bytes, then XOR the row swizzle.
  int a_base[2], a_sw[2];
#pragma unroll
  for (int m = 0; m < 2; ++m) {
    int row   = m * 32 + (lane & 31);
    a_base[m] = row * 128 + ((lane >> 5) * 16);
    a_sw[m]   = (row & 7) << 4;
  }

  // B-fragment pointers: frag n covers cols [bcol + wid*64 + n*32, +32);
  // packed unit (cb32, kg) is lane-linear.
  const unsigned short* bp[2];
#pragma unroll
  for (int n = 0; n < 2; ++n) {
    int cb32 = bcol / 32 + wid * 2 + n;
    bp[n] = Wb + ((size_t)cb32 * KD16 + (size_t)kt0 * 4) * 512 + lane * 8;
  }

  const int br_ = tid >> 2;        // basis row
  const int bd_ = tid & 3;         // basis d-col within the 4-col step
  const float* xrow = X + (size_t)(brow + br_) * DIN + bd_;

  // ---- prologue: X(kt0) + B(kt0) in flight
  float xcur = xrow[(size_t)kt0 * 4];
  short8 bv[4][2];                 // [k-slice][frag] = 8 short8 = 32 VGPR
#pragma unroll
  for (int ks = 0; ks < 4; ++ks)
#pragma unroll
    for (int n = 0; n < 2; ++n)
      bv[ks][n] = *(const short8*)(bp[n] + ks * 512);
#pragma unroll
  for (int n = 0; n < 2; ++n) bp[n] += 2048;

  for (int kt = kt0; kt < kt1; ++kt) {
    __syncthreads();   // prev A-frag reads done

    // ---- stage A: slim basis, swizzled scatter
    {
      float u  = (xcur - KNOT0) * KINVH;
      float uf = floorf(u);
      int   jj = (int)uf;
      float t  = u - uf;
      float s  = 1.0f - t;
      float t2 = t * t, t3 = t2 * t;
      float s2 = s * s, s3 = s2 * s;
      float p0 = s3 * (1.0f / 6.0f);
      float p3 = t3 * (1.0f / 6.0f);
      float p1 = fmaf(0.5f, t3, 2.0f / 3.0f) - t2;
      float p2 = fmaf(0.5f, s3, 2.0f / 3.0f) - s2;

      int base = br_ * 128 + bd_ * 32;
      int sw   = (br_ & 7) << 4;
      *(i32x4*)(smA + (base ^ sw))        = (i32x4){0, 0, 0, 0};
      *(i32x4*)(smA + ((base + 16) ^ sw)) = (i32x4){0, 0, 0, 0};
      unsigned short q0 = f2bf(p0), q1 = f2bf(p1), q2 = f2bf(p2), q3 = f2bf(p3);
      int k0 = jj - 3;
      if ((unsigned)(k0 + 0) < 16u) *(unsigned short*)(smA + ((base + (k0 + 0) * 2) ^ sw)) = q0;
      if ((unsigned)(k0 + 1) < 16u) *(unsigned short*)(smA + ((base + (k0 + 1) * 2) ^ sw)) = q1;
      if ((unsigned)(k0 + 2) < 16u) *(unsigned short*)(smA + ((base + (k0 + 2) * 2) ^ sw)) = q2;
      if ((unsigned)(k0 + 3) < 16u) *(unsigned short*)(smA + ((base + (k0 + 3) * 2) ^ sw)) = q3;
    }

    // prefetch X for next step
    {
      int ktn = (kt + 1 < kt1) ? kt + 1 : kt;
      xcur = xrow[(size_t)ktn * 4];
    }

    __syncthreads();   // A-tile visible

    // ---- compute: 4 k-slices x (2x2) 32x32x16 MFMA
#pragma unroll
    for (int ks = 0; ks < 4; ++ks) {
      short8 a[2];
#pragma unroll
      for (int m = 0; m < 2; ++m)
        a[m] = *(const short8*)(smA + ((a_base[m] + ks * 32) ^ a_sw[m]));
#pragma unroll
      for (int m = 0; m < 2; ++m)
#pragma unroll
        for (int n = 0; n < 2; ++n)
          acc[m][n] = __builtin_amdgcn_mfma_f32_32x32x16_bf16(a[m], bv[ks][n], acc[m][n], 0, 0, 0);
    }

    // issue next-step B loads (WAR after MFMAs; drain at next barrier)
    if (kt + 1 < kt1) {
#pragma unroll
      for (int ks = 0; ks < 4; ++ks)
#pragma unroll
        for (int n = 0; n < 2; ++n)
          bv[ks][n] = *(const short8*)(bp[n] + ks * 512);
#pragma unroll
      for (int n = 0; n < 2; ++n) bp[n] += 2048;
    }
  }

  // ---- epilogue: 32x32 C/D layout (r10-validated):
  // col = lane&31, row = (r&3) + 8*(r>>2) + 4*(lane>>5)
  float* outp = Out + (size_t)blockIdx.z * MROWS * DOUT;
#pragma unroll
  for (int m = 0; m < 2; ++m)
#pragma unroll
    for (int n = 0; n < 2; ++n)
#pragma unroll
      for (int r = 0; r < 16; ++r) {
        int grow = brow + m * 32 + (r & 3) + 8 * (r >> 2) + 4 * (lane >> 5);
        int gcol = bcol + wid * 64 + n * 32 + (lane & 31);
        outp[(size_t)grow * DOUT + gcol] = acc[m][n][r];
      }
}

extern "C" void kernel_launch(void* const* d_in, const int* in_sizes, int n_in,
                              void* d_out, int out_size, void* d_ws, size_t ws_size,
                              hipStream_t stream) {
  const float* x  = (const float*)d_in[0];   // (2,2048,768) f32 -> (4096,768)
  const float* w1 = (const float*)d_in[1];   // (2048,768,16) f32
  const float* w2 = (const float*)d_in[2];   // (768,2048,16) f32
  float* out = (float*)d_out;                // (4096,768) f32

  // ws timeline (128 MiB):
  //   [0, 48M)   : w1b' (phase 1), then w2b' (phase 2, after GEMM1)
  //   [48M, 80M) : GEMM1 partial plane 0 -> becomes h (f32) after reduce2
  //   [80M, 112M): GEMM1 partial plane 1 (dead after reduce2)
  //   [80M, 128M): GEMM2 partial planes 0..3 (overwrites dead plane 1)
  char* ws = (char*)d_ws;
  unsigned short* wgb   = (unsigned short*)ws;                  // 50,331,648 B
  float*          part1 = (float*)(ws + 50331648);              // 2 x 33,554,432 B
  float*          hbf   = part1;                                // alias: plane 0
  float*          part2 = (float*)(ws + 83886080);              // 4 x 12,582,912 B (end = 128MiB)

  // phase 1: layer 1
  {
    const int waves = (HID / 32) * DMODEL;         // 64 * 768 = 49152
    conv_pack32<DMODEL><<<waves / 4, 256, 0, stream>>>(w1, wgb, waves);
  }
  kan_gemm<DMODEL, HID, 2>
      <<<dim3(MROWS / 64, HID / 256, 2), 256, 0, stream>>>(x, wgb, part1);
  const int hn4 = (MROWS * HID) / 4;         // 2,097,152
  reduce2<<<hn4 / 256, 256, 0, stream>>>((float4*)part1, hn4);   // h = plane0

  // phase 2: layer 2 (pack w2 now that w1b' is dead)
  {
    const int waves = (DMODEL / 32) * HID;         // 24 * 2048 = 49152
    conv_pack32<HID><<<waves / 4, 256, 0, stream>>>(w2, wgb, waves);
  }
  kan_gemm<HID, DMODEL, 4>
      <<<dim3(MROWS / 64, DMODEL / 256, 4), 256, 0, stream>>>(hbf, wgb, part2);
  const int rn4 = (MROWS * DMODEL) / 4;      // 786,432
  reduce4<<<rn4 / 256, 256, 0, stream>>>((const float4*)part2, (float4*)out, rn4);
}

// Round 18
// 478.489 us; speedup vs baseline: 3.2913x; 1.0374x over previous
//
#include <hip/hip_runtime.h>
#include <hip/hip_bf16.h>
#include <stdint.h>

typedef __attribute__((ext_vector_type(8))) short short8;
typedef __attribute__((ext_vector_type(4))) float f32x4;
typedef __attribute__((ext_vector_type(4))) int i32x4;

#define DMODEL 768
#define HID    2048
#define MROWS  4096   // 2*2048 tokens

// B-spline constants: h = (4-(-4))/(16-3) = 8/13
#define KINVH  (13.0f/8.0f)
#define KNOT0  (-4.0f - 3.0f*(8.0f/13.0f))

__device__ __forceinline__ unsigned short f2bf(float f) {
  __hip_bfloat16 h = __float2bfloat16(f);   // single v_cvt (RNE)
  return *reinterpret_cast<unsigned short*>(&h);
}

// ---- pack one wave: w[col][k] f32 -> bf16 fragment units (r13 layout) ----
// unit (cb=col/16, kt2=k/32) is 1KB lane-linear: element (q*16+c16) = lane.
template<int DIN>
__device__ __forceinline__ void pack_wave(const float* __restrict__ src,
                                          unsigned short* __restrict__ dst, int gw) {
  constexpr int NK2 = DIN / 2;
  int l   = threadIdx.x & 63;
  int cb  = gw / NK2;
  int kt2 = gw % NK2;
  int c16 = l & 15, q = l >> 4;
  int col = cb * 16 + c16;
  const float* s = src + ((size_t)col * DIN + kt2 * 2 + (q >> 1)) * 16 + (q & 1) * 8;
  float4 v0 = *(const float4*)s;
  float4 v1 = *(const float4*)(s + 4);
  short8 o;
  o[0] = (short)f2bf(v0.x); o[1] = (short)f2bf(v0.y);
  o[2] = (short)f2bf(v0.z); o[3] = (short)f2bf(v0.w);
  o[4] = (short)f2bf(v1.x); o[5] = (short)f2bf(v1.y);
  o[6] = (short)f2bf(v1.z); o[7] = (short)f2bf(v1.w);
  *(short8*)(dst + (((size_t)cb * NK2 + kt2) * 64 + q * 16 + c16) * 8) = o;
}

// ---- phase-1 pack (w1) ----
__global__ void __launch_bounds__(256) conv_pack1(const float* __restrict__ src,
                                                  unsigned short* __restrict__ dst) {
  pack_wave<DMODEL>(src, dst, blockIdx.x * 4 + (threadIdx.x >> 6));
}

// ---- fused phase-2 prep: blocks [0,12288) pack w2; rest do in-place reduce2 ----
__global__ void __launch_bounds__(256) pack2_reduce2(const float* __restrict__ w2,
                                                     unsigned short* __restrict__ dst,
                                                     float4* __restrict__ p, int n4) {
  constexpr int PACK_BLOCKS = ((DMODEL / 16) * (HID / 2)) / 4;   // 12288
  int b = blockIdx.x;
  if (b < PACK_BLOCKS) {
    pack_wave<HID>(w2, dst, b * 4 + (threadIdx.x >> 6));
  } else {
    int i = (b - PACK_BLOCKS) * 256 + threadIdx.x;
    if (i < n4) {
      float4 a = p[i], q = p[i + n4];
      float4 r;
      r.x = a.x + q.x; r.y = a.y + q.y; r.z = a.z + q.z; r.w = a.w + q.w;
      p[i] = r;
    }
  }
}

// ---- split-K=4 reduce: out[i] = sum over 4 planes ----
__global__ void __launch_bounds__(256) reduce4(const float4* __restrict__ p,
                                               float4* __restrict__ out, int n4) {
  int i = blockIdx.x * 256 + threadIdx.x;
  if (i >= n4) return;
  float4 a = p[i], b = p[i + n4], c = p[i + 2 * n4], d = p[i + 3 * n4];
  float4 r;
  r.x = a.x + b.x + c.x + d.x;
  r.y = a.y + b.y + c.y + d.y;
  r.z = a.z + b.z + c.z + d.z;
  r.w = a.w + b.w + c.w + d.w;
  out[i] = r;
}

// ---- fused basis + GEMM: r13 skeleton widened to BK=128 ----
// C[n,o] = sum_{d,k} basis(X[n,d])_k * Wb'[o,k]
// Tile: BM=64 x BN=256, BK=128 (8 x-cols per step). 4 waves in 1x4;
// wave tile 64x64 (FM=FN=4, 16x16x32). 64 MFMA per step between ONE barrier
// pair (r13 had 32): barrier count halves, basis/X boundaries halve.
// B stays 32 VGPR: bv holds 2 kk-chunks; kk2/kk3 reloaded mid-step after
// kk1's MFMAs (77cy cover + multi-wave overlap). A swizzle: (row&15)<<4,
// row&15==lane&15 -> single aswz0 scalar + literal m*4096 + ^(kk<<6);
// conflict-free per 8-lane LDS phase.
template<int DIN, int DOUT, int SPLITK>
__global__ void __launch_bounds__(256, 4)
kan_gemm(const float* __restrict__ X, const unsigned short* __restrict__ Wb,
         float* __restrict__ Out) {
  constexpr int BM  = 64;
  constexpr int BN  = 256;
  constexpr int NK  = (DIN * 16) / 128;    // BK=128 steps
  constexpr int NK2 = DIN / 2;             // packed 32-wide units
  constexpr int NKS = NK / SPLITK;
  constexpr int GX  = MROWS / BM;          // 64
  constexpr int GY  = DOUT / BN;
  constexpr int CPX = (GX * GY) / 8;       // nwg%8==0, bijective
  __shared__ __align__(16) char smA[BM * 256];   // 64 rows x 128 bf16 = 16KB

  const int tid  = threadIdx.x;
  const int lane = tid & 63;
  const int wid  = tid >> 6;

  // XCD-chunked remap
  const int d    = blockIdx.x + blockIdx.y * GX;
  const int lf   = (d & 7) * CPX + (d >> 3);
  const int brow = (lf % GX) * BM;
  const int bcol = (lf / GX) * BN;
  const int kt0  = blockIdx.z * NKS;
  const int kt1  = kt0 + NKS;

  f32x4 acc[4][4];
#pragma unroll
  for (int m = 0; m < 4; ++m)
#pragma unroll
    for (int n = 0; n < 4; ++n) acc[m][n] = (f32x4){0.f, 0.f, 0.f, 0.f};

  // A addressing: base for m=0 with swizzle pre-applied; frag m adds m*4096,
  // k-chunk kk XORs kk<<6 (valid: base bits6,7 = 0, swizzle bits 4-7).
  const int aswz0 = (((lane & 15) * 256) + ((lane >> 4) * 16)) ^ ((lane & 15) << 4);

  // B-fragment pointers (1KB lane-linear units; +2048 shorts per BK=128 step)
  const unsigned short* bp[4];
#pragma unroll
  for (int n = 0; n < 4; ++n)
    bp[n] = Wb + ((size_t)(bcol / 16 + wid * 4 + n) * NK2 + (size_t)kt0 * 4) * 512
               + lane * 8;

  const int br_ = tid >> 3;        // basis row (0..31); second eval row +32
  const int bd_ = tid & 7;         // d-col within the 8-col step
  const float* xrow = X + (size_t)(brow + br_) * DIN + bd_;
  constexpr size_t XO2 = (size_t)32 * DIN;

  // slim basis (r17-validated numerics), swizzled scatter
  auto BASIS = [&](float xv, int row) {
    float u  = (xv - KNOT0) * KINVH;
    float uf = floorf(u);
    int   jj = (int)uf;
    float t  = u - uf;
    float s1 = 1.0f - t;
    float t2 = t * t, t3 = t2 * t;
    float s2 = s1 * s1, s3 = s2 * s1;
    float p0 = s3 * (1.0f / 6.0f);
    float p3 = t3 * (1.0f / 6.0f);
    float p1 = fmaf(0.5f, t3, 2.0f / 3.0f) - t2;
    float p2 = fmaf(0.5f, s3, 2.0f / 3.0f) - s2;

    int base = row * 256 + bd_ * 32;
    int sw   = (row & 15) << 4;
    *(i32x4*)(smA + (base ^ sw))        = (i32x4){0, 0, 0, 0};
    *(i32x4*)(smA + ((base + 16) ^ sw)) = (i32x4){0, 0, 0, 0};
    unsigned short q0 = f2bf(p0), q1 = f2bf(p1), q2 = f2bf(p2), q3 = f2bf(p3);
    int k0 = jj - 3;
    if ((unsigned)(k0 + 0) < 16u) *(unsigned short*)(smA + ((base + (k0 + 0) * 2) ^ sw)) = q0;
    if ((unsigned)(k0 + 1) < 16u) *(unsigned short*)(smA + ((base + (k0 + 1) * 2) ^ sw)) = q1;
    if ((unsigned)(k0 + 2) < 16u) *(unsigned short*)(smA + ((base + (k0 + 2) * 2) ^ sw)) = q2;
    if ((unsigned)(k0 + 3) < 16u) *(unsigned short*)(smA + ((base + (k0 + 3) * 2) ^ sw)) = q3;
  };

  // ---- prologue: X(kt0) + B(kt0, kk0/kk1) in flight
  float xc0 = xrow[(size_t)kt0 * 8];
  float xc1 = xrow[(size_t)kt0 * 8 + XO2];
  short8 bv[2][4];
#pragma unroll
  for (int n = 0; n < 4; ++n) {
    bv[0][n] = *(const short8*)(bp[n]);
    bv[1][n] = *(const short8*)(bp[n] + 512);
  }

  for (int kt = kt0; kt < kt1; ++kt) {
    __syncthreads();   // prev A-frag reads done

    BASIS(xc0, br_);
    BASIS(xc1, br_ + 32);
    {
      int ktn = (kt + 1 < kt1) ? kt + 1 : kt;
      xc0 = xrow[(size_t)ktn * 8];
      xc1 = xrow[(size_t)ktn * 8 + XO2];
    }

    __syncthreads();   // A-tile visible

    short8 a[4];
    // kk=0
#pragma unroll
    for (int m = 0; m < 4; ++m)
      a[m] = *(const short8*)(smA + (aswz0 ^ 0) + m * 4096);
#pragma unroll
    for (int m = 0; m < 4; ++m)
#pragma unroll
      for (int n = 0; n < 4; ++n)
        acc[m][n] = __builtin_amdgcn_mfma_f32_16x16x32_bf16(a[m], bv[0][n], acc[m][n], 0, 0, 0);
    // kk=1
#pragma unroll
    for (int m = 0; m < 4; ++m)
      a[m] = *(const short8*)(smA + (aswz0 ^ 64) + m * 4096);
#pragma unroll
    for (int m = 0; m < 4; ++m)
#pragma unroll
      for (int n = 0; n < 4; ++n)
        acc[m][n] = __builtin_amdgcn_mfma_f32_16x16x32_bf16(a[m], bv[1][n], acc[m][n], 0, 0, 0);

    // mid-step reload: kk2/kk3 into the same bv regs (WAR after kk1 MFMAs)
#pragma unroll
    for (int n = 0; n < 4; ++n) {
      bv[0][n] = *(const short8*)(bp[n] + 1024);
      bv[1][n] = *(const short8*)(bp[n] + 1536);
    }
    // kk=2
#pragma unroll
    for (int m = 0; m < 4; ++m)
      a[m] = *(const short8*)(smA + (aswz0 ^ 128) + m * 4096);
#pragma unroll
    for (int m = 0; m < 4; ++m)
#pragma unroll
      for (int n = 0; n < 4; ++n)
        acc[m][n] = __builtin_amdgcn_mfma_f32_16x16x32_bf16(a[m], bv[0][n], acc[m][n], 0, 0, 0);
    // kk=3
#pragma unroll
    for (int m = 0; m < 4; ++m)
      a[m] = *(const short8*)(smA + (aswz0 ^ 192) + m * 4096);
#pragma unroll
    for (int m = 0; m < 4; ++m)
#pragma unroll
      for (int n = 0; n < 4; ++n)
        acc[m][n] = __builtin_amdgcn_mfma_f32_16x16x32_bf16(a[m], bv[1][n], acc[m][n], 0, 0, 0);

    // next-step kk0/kk1 (latency spans barrier + basis)
    if (kt + 1 < kt1) {
#pragma unroll
      for (int n = 0; n < 4; ++n) {
        bp[n] += 2048;
        bv[0][n] = *(const short8*)(bp[n]);
        bv[1][n] = *(const short8*)(bp[n] + 512);
      }
    }
  }

  // ---- epilogue: C/D layout col=lane&15, row=(lane>>4)*4+q
  float* outp = Out + (size_t)blockIdx.z * MROWS * DOUT;
#pragma unroll
  for (int m = 0; m < 4; ++m)
#pragma unroll
    for (int n = 0; n < 4; ++n)
#pragma unroll
      for (int q = 0; q < 4; ++q) {
        int grow = brow + m * 16 + (lane >> 4) * 4 + q;
        int gcol = bcol + wid * 64 + n * 16 + (lane & 15);
        outp[(size_t)grow * DOUT + gcol] = acc[m][n][q];
      }
}

extern "C" void kernel_launch(void* const* d_in, const int* in_sizes, int n_in,
                              void* d_out, int out_size, void* d_ws, size_t ws_size,
                              hipStream_t stream) {
  const float* x  = (const float*)d_in[0];   // (2,2048,768) f32 -> (4096,768)
  const float* w1 = (const float*)d_in[1];   // (2048,768,16) f32
  const float* w2 = (const float*)d_in[2];   // (768,2048,16) f32
  float* out = (float*)d_out;                // (4096,768) f32

  // ws timeline (128 MiB):
  //   [0, 48M)   : w1b' (phase 1), then w2b' (phase 2, after GEMM1)
  //   [48M, 80M) : GEMM1 partial plane 0 -> becomes h (f32) after reduce2
  //   [80M, 112M): GEMM1 partial plane 1 (dead after reduce2)
  //   [80M, 128M): GEMM2 partial planes 0..3 (overwrites dead plane 1)
  char* ws = (char*)d_ws;
  unsigned short* wgb   = (unsigned short*)ws;                  // 50,331,648 B
  float*          part1 = (float*)(ws + 50331648);              // 2 x 33,554,432 B
  float*          hbf   = part1;                                // alias: plane 0
  float*          part2 = (float*)(ws + 83886080);              // 4 x 12,582,912 B (end = 128MiB)

  // phase 1: pack w1, GEMM1 (split-K=2 partial planes)
  conv_pack1<<<((HID / 16) * (DMODEL / 2)) / 4, 256, 0, stream>>>(w1, wgb);
  kan_gemm<DMODEL, HID, 2>
      <<<dim3(MROWS / 64, HID / 256, 2), 256, 0, stream>>>(x, wgb, part1);

  // phase 2 prep (fused): pack w2 into dead w1b' slot + in-place reduce2 of h
  {
    const int hn4 = (MROWS * HID) / 4;               // 2,097,152
    const int packB = ((DMODEL / 16) * (HID / 2)) / 4;   // 12288
    const int redB  = hn4 / 256;                     // 8192
    pack2_reduce2<<<packB + redB, 256, 0, stream>>>(w2, wgb, (float4*)part1, hn4);
  }
  // GEMM2 (split-K=4 partial planes) + reduce
  kan_gemm<HID, DMODEL, 4>
      <<<dim3(MROWS / 64, DMODEL / 256, 4), 256, 0, stream>>>(hbf, wgb, part2);
  const int rn4 = (MROWS * DMODEL) / 4;      // 786,432
  reduce4<<<rn4 / 256, 256, 0, stream>>>((const float4*)part2, (float4*)out, rn4);
}